// Round 21
// baseline (451.062 us; speedup 1.0000x reference)
//
#include <hip/hip_runtime.h>
#include <stdint.h>

#define NEURONS 512
#define SYN     784
#define TIN     500
#define TP      522
#define TPAD    528
#define BATCH   64
#define NCOL    (BATCH*TPAD)   // 33792
#define XW2     18             // xbT words per (b,*,s): word0 guard, 1..16 data, 17 guard
#define NKK     98             // K iterations (6272 / 64)
#define OUTF4   ((BATCH*NEURONS*TP)/4)  // 4,276,224 float4s in out

typedef int i32x4 __attribute__((ext_vector_type(4)));

// ---------------------------------------------------------------- prep: A pack + spike bits + partial zero + OUT zero (fused; verified R18)
__global__ __launch_bounds__(256) void k_prep(
    const int* __restrict__ w, uint2* __restrict__ apk,
    const float* __restrict__ x, uint32_t* __restrict__ xbT,
    unsigned long long* __restrict__ partial, float4* __restrict__ out4)
{
    __shared__ unsigned char nib[16][128];
    const int bid = blockIdx.x, tid = threadIdx.x;
    if (bid < 1568) {
        // One-hot int8 weights, MFMA-fragment-packed (verified R3/R4).
        int u = bid * 256 + tid;                       // 401408 slots
        int half = u & 1, m = (u >> 1) & 15, quad = (u >> 5) & 3;
        int rowblk = (u >> 7) & 31, kk = u >> 12;
        int n = rowblk * 16 + m;
        int s = kk * 8 + quad * 2 + half;
        int wv = w[n * SYN + s];
        uint2 v;
        v.x = (wv < 4)  ? (1u << (8 * wv))       : 0u;
        v.y = (wv >= 4) ? (1u << (8 * (wv - 4))) : 0u;
        apk[u] = v;
        if (u < NCOL) partial[u] = 0ull;               // fused memset(partial)
    } else if (bid < 4704) {
        // xbT[(b*18 + word)*784 + s]; word 0,17 guards; LDS nibble transpose.
        int r0 = (bid - 1568) * 16;                    // 3136 blocks
        for (int e = tid; e < 2048; e += 256) {
            int row = e >> 7, q4 = e & 127;
            unsigned char v = 0;
            if (q4 < 125) {
                float4 f = *(const float4*)(x + (size_t)(r0 + row) * TIN + q4 * 4);
                v = (unsigned char)((f.x != 0.f) | ((f.y != 0.f) << 1) |
                                    ((f.z != 0.f) << 2) | ((f.w != 0.f) << 3));
            }
            nib[row][q4] = v;
        }
        __syncthreads();
        int row = tid >> 4, d = tid & 15;
        uint64_t u = *(const uint64_t*)&nib[row][d * 8];
        uint32_t wd = 0;
#pragma unroll
        for (int q = 0; q < 8; ++q)
            wd |= ((uint32_t)((u >> (8 * q)) & 0xFull)) << (4 * q);
        if (d == 15) wd &= 0xFFFFFu;                   // taus 480..499 only
        int grow = r0 + row;
        int b = grow / SYN, s = grow - b * SYN;
        xbT[(size_t)(b * XW2 + 1 + d) * SYN + s] = wd;
        if (d == 0) {
            xbT[(size_t)(b * XW2) * SYN + s] = 0u;     // guard word 0
            xbT[(size_t)(b * XW2 + 17) * SYN + s] = 0u;// guard word 17
        }
    } else {
        // out-zero: 512 blocks, grid-stride over 4,276,224 float4 (68 MB)
        const float4 z = make_float4(0.f, 0.f, 0.f, 0.f);
        for (size_t i = (size_t)(bid - 4704) * 256 + tid; i < OUTF4; i += 512 * 256)
            out4[i] = z;
    }
}

// ---------------------------------------------------------------- fused GEMM + argmax
// R21: ROUND-QUANTIZATION fix. R16 (2 blk/CU, 512 resident, 2.06 rounds) and
// R18 (4 blk/CU, 1024 resident, 1024+32 tail) both measured ~228us =>
// per-block time T_b~114us is residency-INVARIANT (latency-chain-bound) and
// both configs run 2 sequential rounds -- R18's round 2 is 32 blocks on 256
// CUs (97% idle for ~114us). Fix: halve the tile to 128x64 -> grid 2112,
// per-wave 16 cols / 1 window / 8 MFMA (acc 32 AGPR, ~85 regs, LDS 26.3KB ->
// 5-6 blk/CU, 1280-1536 resident). Makespan = 2 rounds x T_b(half-work).
// Tables back to uint2 (R20 split: 2x conflict count, zero time change ->
// conflicts off critical path). XCD swizzle: 2112 = 8 x 264, bijective.
__global__ __launch_bounds__(256) void k_gemm_fused2(
    const i32x4*    __restrict__ Apk4,
    const uint32_t* __restrict__ xbT,
    const int*      __restrict__ wk,
    unsigned long long* __restrict__ partial)
{
    __shared__ uint2 T0[2048];           // taps 0..10 sums, packed u8 x8 (per weight)
    __shared__ uint2 T1[1024];           // taps 11..20
    __shared__ unsigned long long red[64 * 4];
    __shared__ uint2 tapv[21];

    const int tid  = threadIdx.x;
    const int lane = tid & 63;
    const int wn   = tid >> 6;
    const int quad = lane >> 4, l15 = lane & 15;

    // XCD-sibling swizzle: 4 rowblk siblings of each colblk adjacent on one XCD.
    const int phys   = blockIdx.x;           // 0..2111
    const int xcd    = phys & 7;
    const int p      = xcd * 264 + (phys >> 3);  // bijective 0..2111
    const int colblk = p >> 2;               // 0..527
    const int rowblk = p & 3;

    const int m0   = rowblk * 128;
    const int col0 = colblk * 64;
    const int rb0  = rowblk * 8;

    if (tid < 21) {
        uint32_t lo = 0, hi = 0;
        for (int q = 0; q < 4; ++q) {
            lo |= ((uint32_t)wk[q * 21 + tid]) << (8 * q);
            hi |= ((uint32_t)wk[(q + 4) * 21 + tid]) << (8 * q);
        }
        tapv[tid] = make_uint2(lo, hi);
    }
    __syncthreads();
    for (int e = tid; e < 3072; e += 256) {
        int base_t = (e < 2048) ? 0 : 11;
        uint32_t mm = (e < 2048) ? e : (e - 2048);
        uint2 a = make_uint2(0u, 0u);
        while (mm) {
            int pp = __builtin_ctz(mm);
            uint2 tv = tapv[base_t + pp];
            a.x += tv.x; a.y += tv.y;
            mm &= mm - 1;
        }
        if (e < 2048) T0[e] = a; else T1[e - 2048] = a;
    }

    // this wave's single 16-col window group
    uint32_t base, sh;
    {
        int c = col0 + wn * 16 + l15;
        int b = c / TPAD, t = c - b * TPAD;
        int bp = t + 11;                 // window covers flat bits bp..bp+20
        base = (uint32_t)((b * XW2 + (bp >> 5)) * SYN + quad * 2);
        sh   = (uint32_t)(bp & 31);
    }
    __syncthreads();

    const uint32_t pa0 = (uint32_t)(rb0 * 64 + lane);

    i32x4 acc[8];
#pragma unroll
    for (int i = 0; i < 8; ++i) { i32x4 z = {0, 0, 0, 0}; acc[i] = z; }

    for (int kk = 0; kk < NKK; ++kk) {
        i32x4 af[8];
#pragma unroll
        for (int i = 0; i < 8; ++i)
            af[i] = Apk4[pa0 + (uint32_t)kk * 2048 + i * 64];
        i32x4 bf;
        {
            const uint2* px = (const uint2*)(xbT + base + kk * 8);
            uint2 lo = px[0];            // word w  : (s0, s1)
            uint2 hi = px[SYN / 2];      // word w+1: (s0, s1)
            uint32_t win0 = __builtin_amdgcn_alignbit(hi.x, lo.x, sh) & 0x1FFFFFu;
            uint32_t win1 = __builtin_amdgcn_alignbit(hi.y, lo.y, sh) & 0x1FFFFFu;
            uint32_t l0 = win0 & 2047u, h0 = win0 >> 11;
            uint32_t l1 = win1 & 2047u, h1 = win1 >> 11;
            uint2 a0 = make_uint2(0u, 0u), a1 = make_uint2(0u, 0u);
            if (l0) { uint2 u = T0[l0]; a0.x += u.x; a0.y += u.y; }   // T0[0]==0: skip
            if (h0) { uint2 v = T1[h0]; a0.x += v.x; a0.y += v.y; }
            if (l1) { uint2 u = T0[l1]; a1.x += u.x; a1.y += u.y; }
            if (h1) { uint2 v = T1[h1]; a1.x += v.x; a1.y += v.y; }
            bf[0] = (int)a0.x; bf[1] = (int)a0.y;
            bf[2] = (int)a1.x; bf[3] = (int)a1.y;
        }
#pragma unroll
        for (int i = 0; i < 8; ++i)
            acc[i] = __builtin_amdgcn_mfma_i32_16x16x64_i8(af[i], bf, acc[i], 0, 0, 0);
    }

    // epilogue: per-lane best over its 32 rows, then cross-quad via LDS
    {
        unsigned long long bp = 0ull;
#pragma unroll
        for (int i = 0; i < 8; ++i)
#pragma unroll
            for (int r = 0; r < 4; ++r) {
                int grow = m0 + i * 16 + quad * 4 + r;
                unsigned long long pk =
                    (((unsigned long long)(uint32_t)acc[i][r]) << 32) |
                    (unsigned long long)(uint32_t)(511 - grow);
                bp = pk > bp ? pk : bp;
            }
        red[(wn * 16 + l15) * 4 + quad] = bp;
    }
    __syncthreads();
    if (tid < 64) {
        unsigned long long b = red[tid * 4];
#pragma unroll
        for (int u = 1; u < 4; ++u) {
            unsigned long long v = red[tid * 4 + u];
            b = v > b ? v : b;
        }
        atomicMax(&partial[col0 + tid], b);
    }
}

// ---------------------------------------------------------------- fire + scan (out zeroed in prep; verified R18)
__global__ __launch_bounds__(256) void k_firescan(
    const unsigned long long* __restrict__ partial, float* __restrict__ out)
{
    __shared__ int argL[576];
    __shared__ unsigned long long fm[9];
    const int b = blockIdx.x, tid = threadIdx.x;
    const int lane = tid & 63, wv = tid >> 6;

    // fire: 9 chunks of 64 t (chunk = p*4 + wave)
#pragma unroll
    for (int p = 0; p < 3; ++p) {
        int chunk = p * 4 + wv;
        if (chunk < 9) {                               // wave-uniform branch
            int t = chunk * 64 + lane;
            int col = b * TPAD + (t < TPAD ? t : TPAD - 1);
            unsigned long long pv = partial[col];
            int best = (int)(pv >> 32);
            argL[t] = 511 - (int)(pv & 0xFFFFFFFFull);
            unsigned long long f = __ballot((t < TP) && (best > 40));
            if (lane == 0) fm[chunk] = f;
        }
    }
    __syncthreads();

    if (tid == 0) {
        unsigned short ts[26];
        int nf = 0, dep = 0;
        for (int c = 0; c < 9; ++c) {
            unsigned long long mm = fm[c];
            int pos = 0;
            while (pos < 64) {
                if (dep > 0) {
                    int adv = dep < (64 - pos) ? dep : (64 - pos);
                    dep -= adv; pos += adv; mm >>= adv;    // adv <= 21 < 64
                    continue;
                }
                if (mm == 0) break;
                int z = __builtin_ctzll(mm);
                pos += z; mm >>= z;
                ts[nf++] = (unsigned short)(c * 64 + pos);
                dep = 21; ++pos; mm >>= 1;
            }
        }
        for (int i = 0; i < nf; ++i) {
            int t = ts[i];
            out[(size_t)b * (NEURONS * TP) + (size_t)argL[t] * TP + t] = 1.0f;
        }
    }
}

extern "C" void kernel_launch(void* const* d_in, const int* in_sizes, int n_in,
                              void* d_out, int out_size, void* d_ws, size_t ws_size,
                              hipStream_t stream) {
    const float* x      = (const float*)d_in[0];
    const int*   weight = (const int*)d_in[1];
    const int*   wk     = (const int*)d_in[2];

    char* ws = (char*)d_ws;
    uint2*              Apk     = (uint2*)(ws);                        // 3,211,264 B
    uint32_t*           xbT     = (uint32_t*)(ws + 3211264);           // 3,612,672 B
    unsigned long long* partial = (unsigned long long*)(ws + 6823936); //   270,336 B
    // total ws need: 7,094,272 B

    float* out = (float*)d_out;

    // 3 dispatches: prep (apack + xbitsT + partial-zero + out-zero),
    // fused GEMM (2112 small tiles), firescan.
    k_prep<<<5216, 256, 0, stream>>>(weight, Apk, x, xbT, partial, (float4*)out);
    k_gemm_fused2<<<2112, 256, 0, stream>>>((const i32x4*)Apk, xbT, wk, partial);
    k_firescan<<<BATCH, 256, 0, stream>>>(partial, out);
}

// Round 22
// 353.666 us; speedup vs baseline: 1.2754x; 1.2754x over previous
//
#include <hip/hip_runtime.h>
#include <stdint.h>

#define NEURONS 512
#define SYN     784
#define TIN     500
#define TP      522
#define TPAD    528
#define TPAD2   576            // padded col space: 576 = 36*16 -> 768-block one-round grid
#define BATCH   64
#define NCOL2   (BATCH*TPAD2)  // 36864
#define XW2B    20             // xbT words per (b,*,s): 0 guard, 1..16 data, 17 guard, 18..19 slack
#define NKK     98             // K iterations (6272 / 64)
#define OUTF4   ((BATCH*NEURONS*TP)/4)  // 4,276,224 float4s in out

typedef int i32x4 __attribute__((ext_vector_type(4)));

// ---------------------------------------------------------------- prep: A pack + spike bits + partial zero + OUT zero (fused)
// blocks 0..1567: apack (+ partial zeroing); 1568..4703: xbitsT; 4704..5215: out-zero.
__global__ __launch_bounds__(256) void k_prep(
    const int* __restrict__ w, uint2* __restrict__ apk,
    const float* __restrict__ x, uint32_t* __restrict__ xbT,
    unsigned long long* __restrict__ partial, float4* __restrict__ out4)
{
    __shared__ unsigned char nib[16][128];
    const int bid = blockIdx.x, tid = threadIdx.x;
    if (bid < 1568) {
        // One-hot int8 weights, MFMA-fragment-packed (verified R3/R4).
        int u = bid * 256 + tid;                       // 401408 slots
        int half = u & 1, m = (u >> 1) & 15, quad = (u >> 5) & 3;
        int rowblk = (u >> 7) & 31, kk = u >> 12;
        int n = rowblk * 16 + m;
        int s = kk * 8 + quad * 2 + half;
        int wv = w[n * SYN + s];
        uint2 v;
        v.x = (wv < 4)  ? (1u << (8 * wv))       : 0u;
        v.y = (wv >= 4) ? (1u << (8 * (wv - 4))) : 0u;
        apk[u] = v;
        if (u < NCOL2) partial[u] = 0ull;              // fused memset(partial, padded)
    } else if (bid < 4704) {
        // xbT[(b*20 + word)*784 + s]; words 0,17 guards; 18,19 slack (only
        // discarded padded columns read them). LDS nibble transpose.
        int r0 = (bid - 1568) * 16;                    // 3136 blocks
        for (int e = tid; e < 2048; e += 256) {
            int row = e >> 7, q4 = e & 127;
            unsigned char v = 0;
            if (q4 < 125) {
                float4 f = *(const float4*)(x + (size_t)(r0 + row) * TIN + q4 * 4);
                v = (unsigned char)((f.x != 0.f) | ((f.y != 0.f) << 1) |
                                    ((f.z != 0.f) << 2) | ((f.w != 0.f) << 3));
            }
            nib[row][q4] = v;
        }
        __syncthreads();
        int row = tid >> 4, d = tid & 15;
        uint64_t u = *(const uint64_t*)&nib[row][d * 8];
        uint32_t wd = 0;
#pragma unroll
        for (int q = 0; q < 8; ++q)
            wd |= ((uint32_t)((u >> (8 * q)) & 0xFull)) << (4 * q);
        if (d == 15) wd &= 0xFFFFFu;                   // taus 480..499 only
        int grow = r0 + row;
        int b = grow / SYN, s = grow - b * SYN;
        xbT[(size_t)(b * XW2B + 1 + d) * SYN + s] = wd;
        if (d == 0) {
            xbT[(size_t)(b * XW2B) * SYN + s] = 0u;      // guard word 0
            xbT[(size_t)(b * XW2B + 17) * SYN + s] = 0u; // guard word 17
        }
    } else {
        // out-zero: 512 blocks, grid-stride over 4,276,224 float4 (68 MB)
        const float4 z = make_float4(0.f, 0.f, 0.f, 0.f);
        for (size_t i = (size_t)(bid - 4704) * 256 + tid; i < OUTF4; i += 512 * 256)
            out4[i] = z;
    }
}

// ---------------------------------------------------------------- fused GEMM + argmax, one-round grid
// R22: ROUND QUANTIZATION fix done right. R16/R18: T_b~114us is co-residency-
// invariant; both paid 2 rounds because 1056 tiles > 1024 resident (R18's
// round 2 = 32 blocks on 256 CUs, 97% idle). 33792 cols (=2^10*33) admits no
// 16-aligned tiling into <=1024 blocks -> PAD cols to 36864 (TPAD2=576=36*16):
// 4 rowblk x 192 colblk(192 cols) = 768 blocks. Per wave 48 cols = 3 windows,
// acc[8][3]=96 AGPR, (256,3) -> 3 blocks/CU -> 768 resident = ONE round.
// Padded cols read in-bounds garbage (20-word xbT stride) and write partial
// slots >=528/batch, which firescan ignores. A-loads amortize over 24 MFMA.
// (R21's half-tiles reverted: doubled per-MFMA overhead, 1.65 rounds.)
__global__ __launch_bounds__(256, 3) void k_gemm_fused4(
    const i32x4*    __restrict__ Apk4,
    const uint32_t* __restrict__ xbT,
    const int*      __restrict__ wk,
    unsigned long long* __restrict__ partial)
{
    __shared__ uint2 T0[2048];           // taps 0..10 sums, packed u8 x8 (per weight)
    __shared__ uint2 T1[1024];           // taps 11..20
    __shared__ unsigned long long red[192 * 4];
    __shared__ uint2 tapv[21];

    const int tid  = threadIdx.x;
    const int lane = tid & 63;
    const int wn   = tid >> 6;
    const int quad = lane >> 4, l15 = lane & 15;

    // XCD-sibling swizzle: 768 = 8 x 96; 4 rowblk siblings of each colblk stay
    // on one XCD, adjacent in launch order (96 % 4 == 0).
    const int phys   = blockIdx.x;           // 0..767
    const int xcd    = phys & 7;
    const int p      = xcd * 96 + (phys >> 3);   // bijective 0..767
    const int colblk = p >> 2;               // 0..191
    const int rowblk = p & 3;

    const int m0   = rowblk * 128;
    const int col0 = colblk * 192;
    const int rb0  = rowblk * 8;

    if (tid < 21) {
        uint32_t lo = 0, hi = 0;
        for (int q = 0; q < 4; ++q) {
            lo |= ((uint32_t)wk[q * 21 + tid]) << (8 * q);
            hi |= ((uint32_t)wk[(q + 4) * 21 + tid]) << (8 * q);
        }
        tapv[tid] = make_uint2(lo, hi);
    }
    __syncthreads();
    for (int e = tid; e < 3072; e += 256) {
        int base_t = (e < 2048) ? 0 : 11;
        uint32_t mm = (e < 2048) ? e : (e - 2048);
        uint2 a = make_uint2(0u, 0u);
        while (mm) {
            int pp = __builtin_ctz(mm);
            uint2 tv = tapv[base_t + pp];
            a.x += tv.x; a.y += tv.y;
            mm &= mm - 1;
        }
        if (e < 2048) T0[e] = a; else T1[e - 2048] = a;
    }

    uint32_t base[3]; uint32_t sh[3];
#pragma unroll
    for (int j = 0; j < 3; ++j) {
        int c = col0 + wn * 48 + j * 16 + l15;
        int b = c / TPAD2, t = c - b * TPAD2;
        int bp = t + 11;                 // window covers flat bits bp..bp+20
        base[j] = (uint32_t)((b * XW2B + (bp >> 5)) * SYN + quad * 2);
        sh[j]   = (uint32_t)(bp & 31);
    }
    __syncthreads();

    const uint32_t pa0 = (uint32_t)(rb0 * 64 + lane);

    i32x4 acc[8][3];
#pragma unroll
    for (int i = 0; i < 8; ++i)
#pragma unroll
        for (int j = 0; j < 3; ++j) { i32x4 z = {0, 0, 0, 0}; acc[i][j] = z; }

    for (int kk = 0; kk < NKK; ++kk) {
        i32x4 af[8];
#pragma unroll
        for (int i = 0; i < 8; ++i)
            af[i] = Apk4[pa0 + (uint32_t)kk * 2048 + i * 64];
        i32x4 bf[3];
#pragma unroll
        for (int j = 0; j < 3; ++j) {
            const uint2* px = (const uint2*)(xbT + base[j] + kk * 8);
            uint2 lo = px[0];            // word w  : (s0, s1)
            uint2 hi = px[SYN / 2];      // word w+1: (s0, s1)
            uint32_t win0 = __builtin_amdgcn_alignbit(hi.x, lo.x, sh[j]) & 0x1FFFFFu;
            uint32_t win1 = __builtin_amdgcn_alignbit(hi.y, lo.y, sh[j]) & 0x1FFFFFu;
            uint32_t l0 = win0 & 2047u, h0 = win0 >> 11;
            uint32_t l1 = win1 & 2047u, h1 = win1 >> 11;
            uint2 a0 = make_uint2(0u, 0u), a1 = make_uint2(0u, 0u);
            if (l0) { uint2 u = T0[l0]; a0.x += u.x; a0.y += u.y; }   // T0[0]==0: skip
            if (h0) { uint2 v = T1[h0]; a0.x += v.x; a0.y += v.y; }
            if (l1) { uint2 u = T0[l1]; a1.x += u.x; a1.y += u.y; }
            if (h1) { uint2 v = T1[h1]; a1.x += v.x; a1.y += v.y; }
            i32x4 bb;
            bb[0] = (int)a0.x; bb[1] = (int)a0.y;
            bb[2] = (int)a1.x; bb[3] = (int)a1.y;
            bf[j] = bb;
        }
#pragma unroll
        for (int i = 0; i < 8; ++i)
#pragma unroll
            for (int j = 0; j < 3; ++j)
                acc[i][j] = __builtin_amdgcn_mfma_i32_16x16x64_i8(af[i], bf[j], acc[i][j], 0, 0, 0);
    }

    // epilogue: per-lane best over its 32 rows per column, cross-quad via LDS
#pragma unroll
    for (int j = 0; j < 3; ++j) {
        unsigned long long bp = 0ull;
#pragma unroll
        for (int i = 0; i < 8; ++i)
#pragma unroll
            for (int r = 0; r < 4; ++r) {
                int grow = m0 + i * 16 + quad * 4 + r;
                unsigned long long pk =
                    (((unsigned long long)(uint32_t)acc[i][j][r]) << 32) |
                    (unsigned long long)(uint32_t)(511 - grow);
                bp = pk > bp ? pk : bp;
            }
        red[(wn * 48 + j * 16 + l15) * 4 + quad] = bp;
    }
    __syncthreads();
    if (tid < 192) {
        unsigned long long b = red[tid * 4];
#pragma unroll
        for (int u = 1; u < 4; ++u) {
            unsigned long long v = red[tid * 4 + u];
            b = v > b ? v : b;
        }
        atomicMax(&partial[col0 + tid], b);
    }
}

// ---------------------------------------------------------------- fire + scan (out zeroed in prep)
// 9 chunks x 64 = 576 = TPAD2 exactly; fire condition still t < TP (522).
__global__ __launch_bounds__(256) void k_firescan(
    const unsigned long long* __restrict__ partial, float* __restrict__ out)
{
    __shared__ int argL[576];
    __shared__ unsigned long long fm[9];
    const int b = blockIdx.x, tid = threadIdx.x;
    const int lane = tid & 63, wv = tid >> 6;

#pragma unroll
    for (int p = 0; p < 3; ++p) {
        int chunk = p * 4 + wv;
        if (chunk < 9) {                               // wave-uniform branch
            int t = chunk * 64 + lane;                 // t in 0..575
            unsigned long long pv = partial[b * TPAD2 + t];
            int best = (int)(pv >> 32);
            argL[t] = 511 - (int)(pv & 0xFFFFFFFFull);
            unsigned long long f = __ballot((t < TP) && (best > 40));
            if (lane == 0) fm[chunk] = f;
        }
    }
    __syncthreads();

    if (tid == 0) {
        unsigned short ts[26];
        int nf = 0, dep = 0;
        for (int c = 0; c < 9; ++c) {
            unsigned long long mm = fm[c];
            int pos = 0;
            while (pos < 64) {
                if (dep > 0) {
                    int adv = dep < (64 - pos) ? dep : (64 - pos);
                    dep -= adv; pos += adv; mm >>= adv;    // adv <= 21 < 64
                    continue;
                }
                if (mm == 0) break;
                int z = __builtin_ctzll(mm);
                pos += z; mm >>= z;
                ts[nf++] = (unsigned short)(c * 64 + pos);
                dep = 21; ++pos; mm >>= 1;
            }
        }
        for (int i = 0; i < nf; ++i) {
            int t = ts[i];
            out[(size_t)b * (NEURONS * TP) + (size_t)argL[t] * TP + t] = 1.0f;
        }
    }
}

extern "C" void kernel_launch(void* const* d_in, const int* in_sizes, int n_in,
                              void* d_out, int out_size, void* d_ws, size_t ws_size,
                              hipStream_t stream) {
    const float* x      = (const float*)d_in[0];
    const int*   weight = (const int*)d_in[1];
    const int*   wk     = (const int*)d_in[2];

    char* ws = (char*)d_ws;
    uint2*              Apk     = (uint2*)(ws);                        // 3,211,264 B
    uint32_t*           xbT     = (uint32_t*)(ws + 3211264);           // 4,014,080 B (20-word stride)
    unsigned long long* partial = (unsigned long long*)(ws + 7225344); //   294,912 B (padded)
    // total ws need: 7,520,256 B

    float* out = (float*)d_out;

    // 3 dispatches: prep (apack + xbitsT + partial-zero + out-zero),
    // fused GEMM (768 one-round tiles), firescan.
    k_prep<<<5216, 256, 0, stream>>>(weight, Apk, x, xbT, partial, (float4*)out);
    k_gemm_fused4<<<768, 256, 0, stream>>>((const i32x4*)Apk, xbT, wk, partial);
    k_firescan<<<BATCH, 256, 0, stream>>>(partial, out);
}

// Round 23
// 336.311 us; speedup vs baseline: 1.3412x; 1.0516x over previous
//
#include <hip/hip_runtime.h>
#include <stdint.h>

#define NEURONS 512
#define SYN     784
#define TIN     500
#define TP      522
#define TPAD    528
#define TPAD2   576            // padded col space: 576 = 36*16 -> 768-block one-round grid
#define BATCH   64
#define NCOL2   (BATCH*TPAD2)  // 36864
#define XW2B    20             // xbT words per (b,*,s): 0 guard, 1..16 data, 17 guard, 18..19 slack
#define NKK     98             // K iterations (6272 / 64)
#define OUTF4   ((BATCH*NEURONS*TP)/4)  // 4,276,224 float4s in out

typedef int i32x4 __attribute__((ext_vector_type(4)));

// ---------------------------------------------------------------- prep: A pack + spike bits + partial zero + OUT zero (fused; verified R22)
__global__ __launch_bounds__(256) void k_prep(
    const int* __restrict__ w, uint2* __restrict__ apk,
    const float* __restrict__ x, uint32_t* __restrict__ xbT,
    unsigned long long* __restrict__ partial, float4* __restrict__ out4)
{
    __shared__ unsigned char nib[16][128];
    const int bid = blockIdx.x, tid = threadIdx.x;
    if (bid < 1568) {
        // One-hot int8 weights, MFMA-fragment-packed (verified R3/R4).
        int u = bid * 256 + tid;                       // 401408 slots
        int half = u & 1, m = (u >> 1) & 15, quad = (u >> 5) & 3;
        int rowblk = (u >> 7) & 31, kk = u >> 12;
        int n = rowblk * 16 + m;
        int s = kk * 8 + quad * 2 + half;
        int wv = w[n * SYN + s];
        uint2 v;
        v.x = (wv < 4)  ? (1u << (8 * wv))       : 0u;
        v.y = (wv >= 4) ? (1u << (8 * (wv - 4))) : 0u;
        apk[u] = v;
        if (u < NCOL2) partial[u] = 0ull;              // fused memset(partial, padded)
    } else if (bid < 4704) {
        // xbT[(b*20 + word)*784 + s]; words 0,17 guards; 18,19 slack (only
        // discarded padded columns read them). LDS nibble transpose.
        int r0 = (bid - 1568) * 16;                    // 3136 blocks
        for (int e = tid; e < 2048; e += 256) {
            int row = e >> 7, q4 = e & 127;
            unsigned char v = 0;
            if (q4 < 125) {
                float4 f = *(const float4*)(x + (size_t)(r0 + row) * TIN + q4 * 4);
                v = (unsigned char)((f.x != 0.f) | ((f.y != 0.f) << 1) |
                                    ((f.z != 0.f) << 2) | ((f.w != 0.f) << 3));
            }
            nib[row][q4] = v;
        }
        __syncthreads();
        int row = tid >> 4, d = tid & 15;
        uint64_t u = *(const uint64_t*)&nib[row][d * 8];
        uint32_t wd = 0;
#pragma unroll
        for (int q = 0; q < 8; ++q)
            wd |= ((uint32_t)((u >> (8 * q)) & 0xFull)) << (4 * q);
        if (d == 15) wd &= 0xFFFFFu;                   // taus 480..499 only
        int grow = r0 + row;
        int b = grow / SYN, s = grow - b * SYN;
        xbT[(size_t)(b * XW2B + 1 + d) * SYN + s] = wd;
        if (d == 0) {
            xbT[(size_t)(b * XW2B) * SYN + s] = 0u;      // guard word 0
            xbT[(size_t)(b * XW2B + 17) * SYN + s] = 0u; // guard word 17
        }
    } else {
        // out-zero: 512 blocks, grid-stride over 4,276,224 float4 (68 MB)
        const float4 z = make_float4(0.f, 0.f, 0.f, 0.f);
        for (size_t i = (size_t)(bid - 4704) * 256 + tid; i < OUTF4; i += 512 * 256)
            out4[i] = z;
    }
}

// ---------------------------------------------------------------- fused GEMM + argmax, one-round grid
// R23 = R22 (177us verified: 768-block one-round grid, TPAD2=576 padding,
// 48 cols / 3 windows / 24 MFMA per wave, (256,3)) with gather PREDICATION
// REMOVED. Justification: R20 proved bank conflicts are off the critical path
// (2x conflicts, zero time delta), and p(all 64 lanes inactive) ~ 0.34^64 ~ 0
// so the wave-level LDS issue always happens anyway -- the 12 per-wave-kk
// cmp/exec-mask sequences were pure overhead (~8-12% of the 1446cy slot).
// T0[0]==T1[0]==0 (table build with mm=0), so inactive lanes add exact zeros.
__global__ __launch_bounds__(256, 3) void k_gemm_fused4(
    const i32x4*    __restrict__ Apk4,
    const uint32_t* __restrict__ xbT,
    const int*      __restrict__ wk,
    unsigned long long* __restrict__ partial)
{
    __shared__ uint2 T0[2048];           // taps 0..10 sums, packed u8 x8 (per weight); T0[0]=0
    __shared__ uint2 T1[1024];           // taps 11..20; T1[0]=0
    __shared__ unsigned long long red[192 * 4];
    __shared__ uint2 tapv[21];

    const int tid  = threadIdx.x;
    const int lane = tid & 63;
    const int wn   = tid >> 6;
    const int quad = lane >> 4, l15 = lane & 15;

    // XCD-sibling swizzle: 768 = 8 x 96; 4 rowblk siblings of each colblk stay
    // on one XCD, adjacent in launch order (96 % 4 == 0).
    const int phys   = blockIdx.x;           // 0..767
    const int xcd    = phys & 7;
    const int p      = xcd * 96 + (phys >> 3);   // bijective 0..767
    const int colblk = p >> 2;               // 0..191
    const int rowblk = p & 3;

    const int m0   = rowblk * 128;
    const int col0 = colblk * 192;
    const int rb0  = rowblk * 8;

    if (tid < 21) {
        uint32_t lo = 0, hi = 0;
        for (int q = 0; q < 4; ++q) {
            lo |= ((uint32_t)wk[q * 21 + tid]) << (8 * q);
            hi |= ((uint32_t)wk[(q + 4) * 21 + tid]) << (8 * q);
        }
        tapv[tid] = make_uint2(lo, hi);
    }
    __syncthreads();
    for (int e = tid; e < 3072; e += 256) {
        int base_t = (e < 2048) ? 0 : 11;
        uint32_t mm = (e < 2048) ? e : (e - 2048);
        uint2 a = make_uint2(0u, 0u);
        while (mm) {
            int pp = __builtin_ctz(mm);
            uint2 tv = tapv[base_t + pp];
            a.x += tv.x; a.y += tv.y;
            mm &= mm - 1;
        }
        if (e < 2048) T0[e] = a; else T1[e - 2048] = a;
    }

    uint32_t base[3]; uint32_t sh[3];
#pragma unroll
    for (int j = 0; j < 3; ++j) {
        int c = col0 + wn * 48 + j * 16 + l15;
        int b = c / TPAD2, t = c - b * TPAD2;
        int bp = t + 11;                 // window covers flat bits bp..bp+20
        base[j] = (uint32_t)((b * XW2B + (bp >> 5)) * SYN + quad * 2);
        sh[j]   = (uint32_t)(bp & 31);
    }
    __syncthreads();

    const uint32_t pa0 = (uint32_t)(rb0 * 64 + lane);

    i32x4 acc[8][3];
#pragma unroll
    for (int i = 0; i < 8; ++i)
#pragma unroll
        for (int j = 0; j < 3; ++j) { i32x4 z = {0, 0, 0, 0}; acc[i][j] = z; }

    for (int kk = 0; kk < NKK; ++kk) {
        i32x4 af[8];
#pragma unroll
        for (int i = 0; i < 8; ++i)
            af[i] = Apk4[pa0 + (uint32_t)kk * 2048 + i * 64];
        i32x4 bf[3];
#pragma unroll
        for (int j = 0; j < 3; ++j) {
            const uint2* px = (const uint2*)(xbT + base[j] + kk * 8);
            uint2 lo = px[0];            // word w  : (s0, s1)
            uint2 hi = px[SYN / 2];      // word w+1: (s0, s1)
            uint32_t win0 = __builtin_amdgcn_alignbit(hi.x, lo.x, sh[j]) & 0x1FFFFFu;
            uint32_t win1 = __builtin_amdgcn_alignbit(hi.y, lo.y, sh[j]) & 0x1FFFFFu;
            uint32_t l0 = win0 & 2047u, h0 = win0 >> 11;
            uint32_t l1 = win1 & 2047u, h1 = win1 >> 11;
            // unconditional gathers: T0[0]==T1[0]==0, zero-index lanes add 0.
            uint2 u0 = T0[l0], v0 = T1[h0];
            uint2 u1 = T0[l1], v1 = T1[h1];
            i32x4 bb;
            bb[0] = (int)(u0.x + v0.x); bb[1] = (int)(u0.y + v0.y);
            bb[2] = (int)(u1.x + v1.x); bb[3] = (int)(u1.y + v1.y);
            bf[j] = bb;
        }
#pragma unroll
        for (int i = 0; i < 8; ++i)
#pragma unroll
            for (int j = 0; j < 3; ++j)
                acc[i][j] = __builtin_amdgcn_mfma_i32_16x16x64_i8(af[i], bf[j], acc[i][j], 0, 0, 0);
    }

    // epilogue: per-lane best over its 32 rows per column, cross-quad via LDS
#pragma unroll
    for (int j = 0; j < 3; ++j) {
        unsigned long long bp = 0ull;
#pragma unroll
        for (int i = 0; i < 8; ++i)
#pragma unroll
            for (int r = 0; r < 4; ++r) {
                int grow = m0 + i * 16 + quad * 4 + r;
                unsigned long long pk =
                    (((unsigned long long)(uint32_t)acc[i][j][r]) << 32) |
                    (unsigned long long)(uint32_t)(511 - grow);
                bp = pk > bp ? pk : bp;
            }
        red[(wn * 48 + j * 16 + l15) * 4 + quad] = bp;
    }
    __syncthreads();
    if (tid < 192) {
        unsigned long long b = red[tid * 4];
#pragma unroll
        for (int u = 1; u < 4; ++u) {
            unsigned long long v = red[tid * 4 + u];
            b = v > b ? v : b;
        }
        atomicMax(&partial[col0 + tid], b);
    }
}

// ---------------------------------------------------------------- fire + scan (out zeroed in prep; verified R22)
// 9 chunks x 64 = 576 = TPAD2 exactly; fire condition still t < TP (522).
__global__ __launch_bounds__(256) void k_firescan(
    const unsigned long long* __restrict__ partial, float* __restrict__ out)
{
    __shared__ int argL[576];
    __shared__ unsigned long long fm[9];
    const int b = blockIdx.x, tid = threadIdx.x;
    const int lane = tid & 63, wv = tid >> 6;

#pragma unroll
    for (int p = 0; p < 3; ++p) {
        int chunk = p * 4 + wv;
        if (chunk < 9) {                               // wave-uniform branch
            int t = chunk * 64 + lane;                 // t in 0..575
            unsigned long long pv = partial[b * TPAD2 + t];
            int best = (int)(pv >> 32);
            argL[t] = 511 - (int)(pv & 0xFFFFFFFFull);
            unsigned long long f = __ballot((t < TP) && (best > 40));
            if (lane == 0) fm[chunk] = f;
        }
    }
    __syncthreads();

    if (tid == 0) {
        unsigned short ts[26];
        int nf = 0, dep = 0;
        for (int c = 0; c < 9; ++c) {
            unsigned long long mm = fm[c];
            int pos = 0;
            while (pos < 64) {
                if (dep > 0) {
                    int adv = dep < (64 - pos) ? dep : (64 - pos);
                    dep -= adv; pos += adv; mm >>= adv;    // adv <= 21 < 64
                    continue;
                }
                if (mm == 0) break;
                int z = __builtin_ctzll(mm);
                pos += z; mm >>= z;
                ts[nf++] = (unsigned short)(c * 64 + pos);
                dep = 21; ++pos; mm >>= 1;
            }
        }
        for (int i = 0; i < nf; ++i) {
            int t = ts[i];
            out[(size_t)b * (NEURONS * TP) + (size_t)argL[t] * TP + t] = 1.0f;
        }
    }
}

extern "C" void kernel_launch(void* const* d_in, const int* in_sizes, int n_in,
                              void* d_out, int out_size, void* d_ws, size_t ws_size,
                              hipStream_t stream) {
    const float* x      = (const float*)d_in[0];
    const int*   weight = (const int*)d_in[1];
    const int*   wk     = (const int*)d_in[2];

    char* ws = (char*)d_ws;
    uint2*              Apk     = (uint2*)(ws);                        // 3,211,264 B
    uint32_t*           xbT     = (uint32_t*)(ws + 3211264);           // 4,014,080 B (20-word stride)
    unsigned long long* partial = (unsigned long long*)(ws + 7225344); //   294,912 B (padded)
    // total ws need: 7,520,256 B

    float* out = (float*)d_out;

    // 3 dispatches: prep (apack + xbitsT + partial-zero + out-zero),
    // fused GEMM (768 one-round tiles), firescan.
    k_prep<<<5216, 256, 0, stream>>>(weight, Apk, x, xbT, partial, (float4*)out);
    k_gemm_fused4<<<768, 256, 0, stream>>>((const i32x4*)Apk, xbT, wk, partial);
    k_firescan<<<BATCH, 256, 0, stream>>>(partial, out);
}